// Round 3
// baseline (557.444 us; speedup 1.0000x reference)
//
#include <hip/hip_runtime.h>

// ---------------------------------------------------------------------------
// TraceSemanticHandshakeV342: fused concat+LayerNorm+Linear+GELU+Linear+GELU
// b=4, m=256, h=64, d=256, CAT=1283.  Rows = b*m*h = 65536.
// One block per (b,m): M=64, N=256, K=1280 bf16 MFMA GEMM, LN in epilogue.
// THIS REVISION: 8-wave blocks (512 thr) to cut per-wave VGPR pressure
// (acc 64->32, g 64->32) so a real 3-deep load pipeline fits in 128 VGPR
// (4 waves/SIMD, 16 waves/CU, enforced by __launch_bounds__(512,4)).
// Double-buffered A tile -> 1 barrier/segment (7 total, was 11).
// LN stats via in-register butterfly shuffle (pst LDS scratch deleted).
// Schedule/seg: MFMA_h1(s) | PACK(s+2) | LOAD(s+3) | MFMA_h2(s) | bar | WRITE(s+2)
// ---------------------------------------------------------------------------

typedef float  f32x4 __attribute__((ext_vector_type(4)));
typedef short  s16x8 __attribute__((ext_vector_type(8)));

__device__ __forceinline__ unsigned short f2bf(float f) {
    unsigned u = __builtin_bit_cast(unsigned, f);
    return (unsigned short)((u + 0x7fffu + ((u >> 16) & 1u)) >> 16);
}
__device__ __forceinline__ unsigned f2bf_pk(float lo, float hi) {
    unsigned ulo = __builtin_bit_cast(unsigned, lo);
    unsigned uhi = __builtin_bit_cast(unsigned, hi);
    ulo = (ulo + 0x7fffu + ((ulo >> 16) & 1u)) >> 16;
    uhi = (uhi + 0x7fffu + ((uhi >> 16) & 1u)) & 0xffff0000u;
    return ulo | uhi;
}
// tanh-form GELU: x*sigmoid(2*0.79788456*(x+0.044715 x^3)); max err ~4e-4.
__device__ __forceinline__ float gelu_t(float x) {
    float u2 = 1.5957691216057308f * x + 0.07135481627f * (x * x * x);
    float e  = __expf(u2);
    float r  = __builtin_amdgcn_rcpf(e + 1.0f);   // 1/(1+e^{2u}) ; e=inf -> 0
    return x - x * r;                              // x*sigmoid(2u)
}

// ---------------------------------------------------------------------------
// Prep: builds in d_ws (no memset / atomics needed any more)
//   w1L bf16 K-blocked: w1L[(kb*256+n)*32+kl] = gamma[k]*W1[k][n], kb<40
//   w2L bf16 K-blocked: w2L[(kb*256+n)*32+kl] = W2[k][n],          kb<8
//   Sg[256], Sb[256] f32: block 48 computes full column sums directly.
// ---------------------------------------------------------------------------
__global__ void __launch_bounds__(256)
prep_k(const float* __restrict__ W1, const float* __restrict__ W2,
       const float* __restrict__ gamma, const float* __restrict__ beta,
       float* __restrict__ Sg, float* __restrict__ Sb,
       short* __restrict__ w1t, short* __restrict__ w2t)
{
    __shared__ float tile[32][257];
    const int blk = blockIdx.x;
    const int t   = threadIdx.x;
    const int nl  = t >> 2, c = t & 3;    // per-wave: contiguous 1KB stores
    if (blk < 40) {
#pragma unroll 4
        for (int kl = 0; kl < 32; ++kl) {
            int k = blk * 32 + kl;
            tile[kl][t] = gamma[k] * W1[k * 256 + t];   // coalesced 1KB row
        }
        __syncthreads();
#pragma unroll
        for (int gi = 0; gi < 4; ++gi) {
            int n = gi * 64 + nl;
            uint4 o;
            o.x = f2bf_pk(tile[c*8+0][n], tile[c*8+1][n]);
            o.y = f2bf_pk(tile[c*8+2][n], tile[c*8+3][n]);
            o.z = f2bf_pk(tile[c*8+4][n], tile[c*8+5][n]);
            o.w = f2bf_pk(tile[c*8+6][n], tile[c*8+7][n]);
            *(uint4*)(w1t + (blk * 256 + n) * 32 + c * 8) = o;
        }
    } else if (blk < 48) {
        const int kb = blk - 40;
#pragma unroll 4
        for (int kl = 0; kl < 32; ++kl) {
            int k = kb * 32 + kl;
            tile[kl][t] = W2[k * 256 + t];
        }
        __syncthreads();
#pragma unroll
        for (int gi = 0; gi < 4; ++gi) {
            int n = gi * 64 + nl;
            uint4 o;
            o.x = f2bf_pk(tile[c*8+0][n], tile[c*8+1][n]);
            o.y = f2bf_pk(tile[c*8+2][n], tile[c*8+3][n]);
            o.z = f2bf_pk(tile[c*8+4][n], tile[c*8+5][n]);
            o.w = f2bf_pk(tile[c*8+6][n], tile[c*8+7][n]);
            *(uint4*)(w2t + (kb * 256 + n) * 32 + c * 8) = o;
        }
    } else {
        // full column sums Sg/Sb (replaces memset+atomics)
        const int n = t;
        float sg = 0.f, sb = 0.f;
#pragma unroll 8
        for (int k = 0; k < 1280; ++k) {
            float w = W1[k * 256 + n];
            sg += gamma[k] * w;
            sb += beta[k]  * w;
        }
        Sg[n] = sg;
        Sb[n] = sb;
    }
}

// ---------------------------------------------------------------------------
// Main fused kernel. grid = 1024 (one per (b,m)); block = 512 (8 waves).
// Wave w: GEMM columns [w*32, w*32+32); staging rows [w*8, w*8+8).
// LDS (66816 B, 2 blocks/CU):
//   bufA/bufB: 2 x [64 rows][32 x 16B chunks bf16, XOR-swz]  @0/@32KB (64KB)
//   phase 2:   y1f f32 [64][256] chunk-of-4 XOR-swz aliases bufA+bufB
//   stats:     mu/rs/t0/t1/t2 [64] each                      @64KB (1.25KB)
// ---------------------------------------------------------------------------
__global__ void __launch_bounds__(512, 4)
fused_main(const float* __restrict__ token, const float* __restrict__ step,
           const float* __restrict__ dyn,   const float* __restrict__ sem,
           const float* __restrict__ trace, const float* __restrict__ rel,
           const float* __restrict__ vis,   const float* __restrict__ gamma,
           const float* __restrict__ beta,  const float* __restrict__ W1,
           const float* __restrict__ b1v,   const float* __restrict__ b2v,
           const float* __restrict__ Sg,    const float* __restrict__ Sb,
           const short* __restrict__ w1t,   const short* __restrict__ w2t,
           float* __restrict__ out)
{
    __shared__ __align__(16) char lds_raw[66816];
    uint4* bufA               = (uint4*)lds_raw;                 // 32 KB
    uint4* bufB               = (uint4*)(lds_raw + 32768);       // 32 KB
    unsigned long long* bufA8 = (unsigned long long*)lds_raw;
    unsigned long long* bufB8 = (unsigned long long*)(lds_raw + 32768);
    float* y1f                = (float*)lds_raw;                 // 64 KB (phase 2)
    float* mu_s               = (float*)(lds_raw + 65536);
    float* rs_s               = mu_s + 64;
    float* t0s                = mu_s + 128;
    float* t1s                = mu_s + 192;
    float* t2s                = mu_s + 256;

    const int t    = threadIdx.x;
    const int bm   = blockIdx.x;          // b*256 + m
    const int b_i  = bm >> 8;
    const int lane = t & 63;
    const int wv   = t >> 6;              // 0..7
    const int l15  = lane & 15;
    const int q    = lane >> 4;
    const int sw   = l15 & 7;             // A-read swizzle key (m&7 == l15&7)
    const int n0   = wv * 32;             // GEMM column base (2 x 16)
    const int r0   = wv * 8;              // staging row base

    const float* base0 = token + bm * 256;                  // stride 0
    const float* base1 = step  + (b_i * 64 + r0) * 256;
    const float* base2 = dyn   + (bm * 64 + r0) * 256;
    const float* base3 = sem   + (bm * 64 + r0) * 256;
    const float* base4 = trace + (bm * 64 + r0) * 256;

    f32x4 acc[2][2];
    float s1[8], s2[8];
    float4 g[8];
    unsigned long long pk[8];
#pragma unroll
    for (int i = 0; i < 2; ++i)
#pragma unroll
        for (int j = 0; j < 2; ++j)
            acc[i][j] = (f32x4){0.f, 0.f, 0.f, 0.f};
    // NOTE: acc covers mt 0..3 via two passes below?  NO -- acc must cover all
    // 4 mt.  Use acc4[4][2]:
    f32x4 acc4[4][2];
#pragma unroll
    for (int i = 0; i < 4; ++i)
#pragma unroll
        for (int j = 0; j < 2; ++j)
            acc4[i][j] = (f32x4){0.f, 0.f, 0.f, 0.f};
#pragma unroll
    for (int j = 0; j < 8; ++j) { s1[j] = 0.f; s2[j] = 0.f; }

#define LOADSEG(BASE, STRIDE)                                                  \
    _Pragma("unroll")                                                          \
    for (int j = 0; j < 8; ++j)                                                \
        g[j] = *((const float4*)((BASE) + j * (STRIDE)) + lane);

#define PACKSEG()                                                              \
    _Pragma("unroll")                                                          \
    for (int j = 0; j < 8; ++j) {                                              \
        float4 v = g[j];                                                       \
        s1[j] += v.x + v.y + v.z + v.w;                                        \
        s2[j] += v.x*v.x + v.y*v.y + v.z*v.z + v.w*v.w;                        \
        pk[j] = (unsigned long long)f2bf_pk(v.x, v.y)                          \
              | ((unsigned long long)f2bf_pk(v.z, v.w) << 32);                 \
    }

#define WRITESEG(BUF8)                                                         \
    _Pragma("unroll")                                                          \
    for (int j = 0; j < 8; ++j)                                                \
        (BUF8)[((r0 + j) * 32 + ((lane >> 1) ^ j)) * 2 + (lane & 1)] = pk[j];

    // One K-chunk (32 k) of GEMM1 on buffer BUF for segment SEG.
#define G1_KC(SEG, KC, BUF)                                                    \
    do {                                                                       \
        const short* wk_ = w1t + ((SEG) * 8 + (KC)) * 8192;                    \
        s16x8 b0 = *(const s16x8*)(wk_ + (n0 + l15) * 32 + q * 8);             \
        s16x8 b1 = *(const s16x8*)(wk_ + (n0 + 16 + l15) * 32 + q * 8);        \
        s16x8 a0 = *(const s16x8*)&(BUF)[( 0 + l15) * 32 + (((KC)*4+q) ^ sw)]; \
        s16x8 a1 = *(const s16x8*)&(BUF)[(16 + l15) * 32 + (((KC)*4+q) ^ sw)]; \
        __builtin_amdgcn_s_setprio(1);                                         \
        acc4[0][0] = __builtin_amdgcn_mfma_f32_16x16x32_bf16(a0, b0, acc4[0][0], 0,0,0); \
        acc4[0][1] = __builtin_amdgcn_mfma_f32_16x16x32_bf16(a0, b1, acc4[0][1], 0,0,0); \
        acc4[1][0] = __builtin_amdgcn_mfma_f32_16x16x32_bf16(a1, b0, acc4[1][0], 0,0,0); \
        acc4[1][1] = __builtin_amdgcn_mfma_f32_16x16x32_bf16(a1, b1, acc4[1][1], 0,0,0); \
        __builtin_amdgcn_s_setprio(0);                                         \
        s16x8 a2 = *(const s16x8*)&(BUF)[(32 + l15) * 32 + (((KC)*4+q) ^ sw)]; \
        s16x8 a3 = *(const s16x8*)&(BUF)[(48 + l15) * 32 + (((KC)*4+q) ^ sw)]; \
        __builtin_amdgcn_s_setprio(1);                                         \
        acc4[2][0] = __builtin_amdgcn_mfma_f32_16x16x32_bf16(a2, b0, acc4[2][0], 0,0,0); \
        acc4[2][1] = __builtin_amdgcn_mfma_f32_16x16x32_bf16(a2, b1, acc4[2][1], 0,0,0); \
        acc4[3][0] = __builtin_amdgcn_mfma_f32_16x16x32_bf16(a3, b0, acc4[3][0], 0,0,0); \
        acc4[3][1] = __builtin_amdgcn_mfma_f32_16x16x32_bf16(a3, b1, acc4[3][1], 0,0,0); \
        __builtin_amdgcn_s_setprio(0);                                         \
    } while (0)

#define G1_HALF1(SEG, BUF) do { G1_KC(SEG,0,BUF); G1_KC(SEG,1,BUF); G1_KC(SEG,2,BUF); G1_KC(SEG,3,BUF); } while (0)
#define G1_HALF2(SEG, BUF) do { G1_KC(SEG,4,BUF); G1_KC(SEG,5,BUF); G1_KC(SEG,6,BUF); G1_KC(SEG,7,BUF); } while (0)

    // ---- prologue: fill buf0 (seg0), buf1 (seg1), issue load seg2 ---------
    LOADSEG(base0, 0);      PACKSEG();  WRITESEG(bufA8);
    LOADSEG(base1, 256);    PACKSEG();  WRITESEG(bufB8);
    LOADSEG(base2, 256);
    __syncthreads();

    // ---- steady pipeline: 1 barrier per segment ---------------------------
    // iter 0: compute seg0, pack seg2, load seg3, write seg2 -> bufA
    G1_HALF1(0, bufA);  PACKSEG();  LOADSEG(base3, 256);  G1_HALF2(0, bufA);
    __syncthreads();
    WRITESEG(bufA8);
    // iter 1: compute seg1, pack seg3, load seg4, write seg3 -> bufB
    G1_HALF1(1, bufB);  PACKSEG();  LOADSEG(base4, 256);  G1_HALF2(1, bufB);
    __syncthreads();
    WRITESEG(bufB8);
    // iter 2: compute seg2, pack seg4, write seg4 -> bufA
    G1_HALF1(2, bufA);  PACKSEG();                        G1_HALF2(2, bufA);
    __syncthreads();
    WRITESEG(bufA8);
    // iter 3: compute seg3
    G1_HALF1(3, bufB);  G1_HALF2(3, bufB);
    __syncthreads();                       // separates WRITE(seg4) from readers
    // iter 4: compute seg4
    G1_HALF1(4, bufA);  G1_HALF2(4, bufA);

    // ---- LN stats: butterfly reduce across the wave -----------------------
#pragma unroll
    for (int j = 0; j < 8; ++j) {
#pragma unroll
        for (int d = 1; d < 64; d <<= 1) {
            s1[j] += __shfl_xor(s1[j], d);
            s2[j] += __shfl_xor(s2[j], d);
        }
    }
    {   // lane k (k<8) handles row r0+k; pick s[k] via static select chain
        float S1v = s1[0], S2v = s2[0];
        const int rsel = lane & 7;
#pragma unroll
        for (int j = 1; j < 8; ++j) {
            bool p = (rsel == j);
            S1v = p ? s1[j] : S1v;
            S2v = p ? s2[j] : S2v;
        }
        if (lane < 8) {
            const int r = r0 + rsel;
            float2 rl = *(const float2*)(rel + (bm * 64 + r) * 2);
            float x2  = vis[bm * 64 + r];
            float S1 = S1v + rl.x + rl.y + x2;
            float S2 = S2v + rl.x * rl.x + rl.y * rl.y + x2 * x2;
            const float inv = 1.0f / 1283.0f;
            float mu  = S1 * inv;
            float var = S2 * inv - mu * mu;
            float rs  = rsqrtf(var + 1e-5f);
            mu_s[r] = mu;
            rs_s[r] = rs;
            t0s[r] = (rl.x - mu) * rs * gamma[1280] + beta[1280];
            t1s[r] = (rl.y - mu) * rs * gamma[1281] + beta[1281];
            t2s[r] = (x2   - mu) * rs * gamma[1282] + beta[1282];
        }
    }
    __syncthreads();    // stats visible; all waves past MFMA(4) -> y1f safe

    // ---- epilogue 1: LN fixup + tail + bias + GELU -> y1 f32 (swizzled) ---
#pragma unroll
    for (int nt = 0; nt < 2; ++nt) {
        int n = n0 + nt * 16 + l15;
        float sg  = Sg[n], sb = Sb[n], bb = b1v[n];
        float wt0 = W1[1280 * 256 + n];
        float wt1 = W1[1281 * 256 + n];
        float wt2 = W1[1282 * 256 + n];
#pragma unroll
        for (int mt = 0; mt < 4; ++mt) {
#pragma unroll
            for (int r4 = 0; r4 < 4; ++r4) {
                int r = mt * 16 + q * 4 + r4;
                float rsv = rs_s[r], muv = mu_s[r];
                float v = rsv * acc4[mt][nt][r4] - rsv * muv * sg + sb + bb
                        + t0s[r] * wt0 + t1s[r] * wt1 + t2s[r] * wt2;
                v = gelu_t(v);
                y1f[r * 256 + ((((n >> 2) ^ (r & 7)) << 2) | (n & 3))] = v;
            }
        }
    }
    __syncthreads();

    // ---- GEMM2: y1 (f32 in LDS, cvt at read) @ w2L (coalesced global) -----
    f32x4 acc2[4][2];
#pragma unroll
    for (int i = 0; i < 4; ++i)
#pragma unroll
        for (int j = 0; j < 2; ++j)
            acc2[i][j] = (f32x4){0.f, 0.f, 0.f, 0.f};

#pragma unroll
    for (int kc = 0; kc < 8; ++kc) {
        const short* wk = w2t + kc * 8192;
        s16x8 b0 = *(const s16x8*)(wk + (n0 + l15) * 32 + q * 8);
        s16x8 b1 = *(const s16x8*)(wk + (n0 + 16 + l15) * 32 + q * 8);
        s16x8 afr[4];
#pragma unroll
        for (int mt = 0; mt < 4; ++mt) {
            int m  = mt * 16 + l15;
            int s  = m & 7;
            int c0 = kc * 8 + q * 2;   // even 4-f32-chunk index
            const f32x4 lo = *(const f32x4*)&y1f[m * 256 + ((c0 ^ s) << 2)];
            const f32x4 hi = *(const f32x4*)&y1f[m * 256 + (((c0 + 1) ^ s) << 2)];
            unsigned p0, p1, p2, p3;
            asm("v_cvt_pk_bf16_f32 %0, %1, %2" : "=v"(p0) : "v"(lo[0]), "v"(lo[1]));
            asm("v_cvt_pk_bf16_f32 %0, %1, %2" : "=v"(p1) : "v"(lo[2]), "v"(lo[3]));
            asm("v_cvt_pk_bf16_f32 %0, %1, %2" : "=v"(p2) : "v"(hi[0]), "v"(hi[1]));
            asm("v_cvt_pk_bf16_f32 %0, %1, %2" : "=v"(p3) : "v"(hi[2]), "v"(hi[3]));
            uint4 u;
            u.x = p0; u.y = p1; u.z = p2; u.w = p3;
            afr[mt] = __builtin_bit_cast(s16x8, u);
        }
        __builtin_amdgcn_s_setprio(1);
#pragma unroll
        for (int mt = 0; mt < 4; ++mt) {
            acc2[mt][0] = __builtin_amdgcn_mfma_f32_16x16x32_bf16(afr[mt], b0, acc2[mt][0], 0,0,0);
            acc2[mt][1] = __builtin_amdgcn_mfma_f32_16x16x32_bf16(afr[mt], b1, acc2[mt][1], 0,0,0);
        }
        __builtin_amdgcn_s_setprio(0);
    }

    // ---- epilogue 2: + b2, GELU, store f32 --------------------------------
#pragma unroll
    for (int nt = 0; nt < 2; ++nt) {
        int n = n0 + nt * 16 + l15;
        float bb = b2v[n];
#pragma unroll
        for (int mt = 0; mt < 4; ++mt)
#pragma unroll
            for (int r4 = 0; r4 < 4; ++r4) {
                int r = mt * 16 + q * 4 + r4;
                out[(bm * 64 + r) * 256 + n] = gelu_t(acc2[mt][nt][r4] + bb);
            }
    }
#undef LOADSEG
#undef PACKSEG
#undef WRITESEG
#undef G1_KC
#undef G1_HALF1
#undef G1_HALF2
}

// ---------------------------------------------------------------------------
extern "C" void kernel_launch(void* const* d_in, const int* in_sizes, int n_in,
                              void* d_out, int out_size, void* d_ws, size_t ws_size,
                              hipStream_t stream) {
    const float* token = (const float*)d_in[0];
    const float* step  = (const float*)d_in[1];
    const float* dyn   = (const float*)d_in[2];
    const float* sem   = (const float*)d_in[3];
    const float* trace = (const float*)d_in[4];
    const float* rel   = (const float*)d_in[5];
    const float* vis   = (const float*)d_in[6];
    const float* gamma = (const float*)d_in[7];
    const float* beta  = (const float*)d_in[8];
    const float* W1    = (const float*)d_in[9];
    const float* b1    = (const float*)d_in[10];
    const float* W2    = (const float*)d_in[11];
    const float* b2    = (const float*)d_in[12];

    // ws layout: [0,1KB) Sg f32, [1KB,2KB) Sb f32, then w1L bf16 (655360 B),
    // then w2L bf16 (131072 B).  Total 788480 B.
    float* Sg  = (float*)d_ws;
    float* Sb  = Sg + 256;
    short* w1t = (short*)((char*)d_ws + 2048);
    short* w2t = w1t + 1280 * 256;
    float* out = (float*)d_out;

    hipLaunchKernelGGL(prep_k, dim3(49), dim3(256), 0, stream,
                       W1, W2, gamma, beta, Sg, Sb, w1t, w2t);
    hipLaunchKernelGGL(fused_main, dim3(1024), dim3(512), 0, stream,
                       token, step, dyn, sem, trace, rel, vis, gamma, beta,
                       W1, b1, b2, Sg, Sb, w1t, w2t, out);
}